// Round 1
// 196.309 us; speedup vs baseline: 1.1009x; 1.1009x over previous
//
#include <hip/hip_runtime.h>
#include <hip/hip_bf16.h>

#define DIM 1024
#define NH 16
#define HD 64
#define BB 2
#define SS 2048
#define MROWS (BB * SS)   // 4096
#define SCALE 0.03125f    // 1024^-0.5
#define SC_LOG2E 0.04508422002778011f  // SCALE * log2(e)

typedef unsigned short u16;
typedef unsigned int u32;
typedef __attribute__((ext_vector_type(8))) short short8;
typedef __attribute__((ext_vector_type(4))) float f32x4;

#if __has_builtin(__builtin_amdgcn_exp2f)
#define EXP2(x) __builtin_amdgcn_exp2f(x)
#else
#define EXP2(x) __builtin_exp2f(x)
#endif

__device__ __forceinline__ u16 f2bf(float f) {
  union { float f; u32 u; } v; v.f = f;
  return (u16)((v.u + 0x7fffu + ((v.u >> 16) & 1u)) >> 16);
}

__device__ __forceinline__ u32 pack2bf(float a, float b) {
  union { __hip_bfloat162 h; u32 u; } cv;
  cv.h = __float22bfloat162_rn(make_float2(a, b));
  return cv.u;
}

__device__ __forceinline__ void async16(const u16* g, u16* l) {
  __builtin_amdgcn_global_load_lds(
      (const __attribute__((address_space(1))) void*)(const void*)g,
      (__attribute__((address_space(3))) void*)(void*)l, 16, 0, 0);
}

__device__ __forceinline__ short8 ld8(const u16* p) { return *(const short8*)p; }

// ---------------- fp32 -> bf16 convert (vectorized) ----------------
__global__ void cvt_kernel(const float* __restrict__ in, u16* __restrict__ out, int n4) {
  int i = blockIdx.x * blockDim.x + threadIdx.x;
  if (i < n4) {
    float4 v = ((const float4*)in)[i];
    u32 lo = (u32)f2bf(v.x) | ((u32)f2bf(v.y) << 16);
    u32 hi = (u32)f2bf(v.z) | ((u32)f2bf(v.w) << 16);
    ((uint2*)out)[i] = make_uint2(lo, hi);
  }
}

// ------- transpose + convert: in fp32 [R][C] -> out bf16 [C][R] -------
__global__ void tconv_kernel(const float* __restrict__ in, u16* __restrict__ out, int R, int C) {
  __shared__ u16 t[64 * 65];
  int c0 = blockIdx.x * 64, r0 = blockIdx.y * 64;
  #pragma unroll
  for (int i = 0; i < 16; i++) {
    int j = i * 256 + threadIdx.x;
    int rr = j >> 6, cc = j & 63;
    t[rr * 65 + cc] = f2bf(in[(size_t)(r0 + rr) * C + c0 + cc]);
  }
  __syncthreads();
  #pragma unroll
  for (int i = 0; i < 16; i++) {
    int j = i * 256 + threadIdx.x;
    int oc = j >> 6, orr = j & 63;
    out[(size_t)(c0 + oc) * R + r0 + orr] = t[orr * 65 + oc];
  }
}

// ------- bf16 GEMM, m97 structure: C[M,N] = A[M,K] @ Bt[N,K]^T + bias -------
// MODE 0: QKV gemm -> Q,K cols to qk2 [4096][2048] (stride-2048, V holes removed),
//         Q pre-scaled by SCALE*log2(e) so attn can use raw v_exp_f32.
//         V cols packed-transposed to vT [b][h][d][s].
// MODE 1: plain fp32 output [M][N].
template <int MODE>
__global__ __launch_bounds__(256, 2) void gemm_bt(
    const u16* __restrict__ A, const u16* __restrict__ Bt,
    const float* __restrict__ bias, void* __restrict__ C,
    u16* __restrict__ vT, int M, int N, int K) {
  __shared__ __align__(16) u16 As[128 * 32];
  __shared__ __align__(16) u16 Bs[128 * 32];
  const int tid = threadIdx.x;
  const int w = tid >> 6, l = tid & 63;
  const int r = l & 15, q = l >> 4;
  const int m0 = blockIdx.y * 128, n0 = blockIdx.x * 128;
  const int qm = (w & 1) * 64, qn = (w >> 1) * 64;

  const size_t aoff = (size_t)(m0 + w * 16 + (l >> 2)) * K + (size_t)(l & 3) * 8;
  const size_t boff = (size_t)(n0 + w * 16 + (l >> 2)) * K + (size_t)(l & 3) * 8;
  u16* alds = &As[(w * 64 + l) * 8];
  u16* blds = &Bs[(w * 64 + l) * 8];

  f32x4 acc[4][4] = {};
  for (int k0 = 0; k0 < K; k0 += 32) {
    async16(A + aoff + k0, alds);
    async16(A + aoff + (size_t)64 * K + k0, alds + 2048);
    async16(Bt + boff + k0, blds);
    async16(Bt + boff + (size_t)64 * K + k0, blds + 2048);
    __syncthreads();
    short8 af[4], bfr[4];
    #pragma unroll
    for (int i = 0; i < 4; i++) af[i] = ld8(&As[(qm + i * 16 + r) * 32 + q * 8]);
    #pragma unroll
    for (int j = 0; j < 4; j++) bfr[j] = ld8(&Bs[(qn + j * 16 + r) * 32 + q * 8]);
    #pragma unroll
    for (int i = 0; i < 4; i++)
      #pragma unroll
      for (int j = 0; j < 4; j++)
        acc[i][j] = __builtin_amdgcn_mfma_f32_16x16x32_bf16(af[i], bfr[j], acc[i][j], 0, 0, 0);
    __syncthreads();
  }
  // epilogue: C layout col = lane&15, row = quad*4 + reg
  #pragma unroll
  for (int i = 0; i < 4; i++) {
    int ro = m0 + qm + i * 16 + q * 4;
    #pragma unroll
    for (int j = 0; j < 4; j++) {
      int col = n0 + qn + j * 16 + r;
      float bv = bias[col];
      float v0 = acc[i][j][0] + bv, v1 = acc[i][j][1] + bv;
      float v2 = acc[i][j][2] + bv, v3 = acc[i][j][3] + bv;
      if (MODE == 1) {
        float* out = (float*)C;
        out[(size_t)(ro + 0) * N + col] = v0;
        out[(size_t)(ro + 1) * N + col] = v1;
        out[(size_t)(ro + 2) * N + col] = v2;
        out[(size_t)(ro + 3) * N + col] = v3;
      } else {
        int h = col / 192, wi = col - h * 192;
        if (wi >= 128) {
          // V: packed-transposed store, vT[((b*NH+h)*HD + d)*SS + s], 4 s's contiguous
          int bb = ro >> 11, s = ro & 2047, d = wi - 128;
          uint2 pk = make_uint2(pack2bf(v0, v1), pack2bf(v2, v3));
          *(uint2*)&vT[((size_t)((bb * NH + h) * HD + d)) * SS + s] = pk;
        } else {
          u16* qk2 = (u16*)C;
          const float sc = (wi < 64) ? SC_LOG2E : 1.0f;  // pre-scale Q only
          qk2[(size_t)(ro + 0) * 2048 + h * 128 + wi] = f2bf(v0 * sc);
          qk2[(size_t)(ro + 1) * 2048 + h * 128 + wi] = f2bf(v1 * sc);
          qk2[(size_t)(ro + 2) * 2048 + h * 128 + wi] = f2bf(v2 * sc);
          qk2[(size_t)(ro + 3) * 2048 + h * 128 + wi] = f2bf(v3 * sc);
        }
      }
    }
  }
}

// ------------------------- fused attention v4 -------------------------
// 512 threads = 8 waves, 2 blocks/CU -> 16 waves/CU (4/SIMD, 2x attn3).
// Waves split the KV tile s-axis: wave (ws,wq), ws=w>>2 handles s-half
// ws*64..+63, wq=w&3 handles q rows wq*32..+31. Same K/V LDS layout+swizzle
// as attn3; per-wave private P buffer [32][72] (stride 72 -> conflict-free
// b128 reads). Softmax denominator via extra MFMA against a ones fragment
// (no VALU adds, no shuffles; denom lands in the consuming lane/element).
// Q was pre-scaled by SCALE*log2e in gemm, so P = exp2(S) directly.
// Epilogue: s-halves exchange partial O (32x32 f32 each) + denom through
// reused LDS; each wave stores its own 32-column half.
__global__ __launch_bounds__(512, 4) void attn4_kernel(
    const u16* __restrict__ qk2, const u16* __restrict__ vT,
    u16* __restrict__ attno) {
  __shared__ __align__(16) u16 smem[34816];  // 69632 B: Ks 16K | Vs 16K | pb 36K
  u16* Ks = smem;           // [128][64], slot c' of row s holds chunk c'^(s&7)
  u16* Vs = smem + 8192;    // [64][128], slot c' of row d holds chunk c'^(d&15)
  const int tid = threadIdx.x;
  const int w = tid >> 6, l = tid & 63;
  const int r = l & 15, q = l >> 4;
  const int wq = w & 3, ws = w >> 2;
  const int b = blockIdx.z, h = blockIdx.y, q0 = blockIdx.x * 128;

  const u16* qb = qk2 + (size_t)b * SS * 2048;
  const u16* kB = qb + h * 128 + 64;
  const u16* vB = vT + (size_t)((b * NH + h) * HD) * SS;
  u16* pw = smem + 16384 + w * (32 * 72);

  // Q fragments (B-operand): rows q0+wq*32+i*16+r, k = kq*32+q*8 (pre-scaled)
  short8 qf[2][2];
  #pragma unroll
  for (int i = 0; i < 2; i++)
    #pragma unroll
    for (int kq = 0; kq < 2; kq++)
      qf[i][kq] = ld8(qb + (size_t)(q0 + wq * 32 + i * 16 + r) * 2048 + h * 128 + kq * 32 + q * 8);

  // staging lane constants
  const int klrow = l >> 3;                 // K: row within 8-row group
  const int kchunk = (l & 7) ^ klrow;       // K: swizzled global 16B-chunk
  const int vlrow = l >> 4;                 // V: row within 4-row group
  const int vslot = l & 15;                 // V: LDS slot

  const short8 vone = {0x3F80, 0x3F80, 0x3F80, 0x3F80, 0x3F80, 0x3F80, 0x3F80, 0x3F80};
  f32x4 oacc[2][4] = {};
  f32x4 den[2] = {};

  for (int kv0 = 0; kv0 < SS; kv0 += 128) {
    // ---- stage K tile (128x64) + V^T tile (64x128), 4 instrs/wave ----
    #pragma unroll
    for (int t = 0; t < 2; t++) {
      int g = w * 2 + t;
      async16(kB + (size_t)(kv0 + g * 8 + klrow) * 2048 + kchunk * 8, &Ks[g * 512 + l * 8]);
    }
    #pragma unroll
    for (int t = 0; t < 2; t++) {
      int g = w * 2 + t;
      int d = g * 4 + vlrow;
      int c = vslot ^ (d & 15);
      async16(vB + (size_t)d * SS + kv0 + c * 8, &Vs[g * 512 + l * 8]);
    }
    __syncthreads();   // drains vmcnt (compiler emits waitcnt before barrier)

    // ---- S^T = K Q^T over own s-half: A = K rows (m=s), B = Q regs (n=q) ----
    f32x4 sacc[4][2] = {};
    #pragma unroll
    for (int j2 = 0; j2 < 4; j2++) {
      const u16* krow = &Ks[(ws * 64 + j2 * 16 + r) * 64];
      short8 a0 = ld8(krow + ((q ^ (r & 7)) * 8));
      short8 a1 = ld8(krow + (((4 + q) ^ (r & 7)) * 8));
      #pragma unroll
      for (int i = 0; i < 2; i++) {
        sacc[j2][i] = __builtin_amdgcn_mfma_f32_16x16x32_bf16(a0, qf[i][0], sacc[j2][i], 0, 0, 0);
        sacc[j2][i] = __builtin_amdgcn_mfma_f32_16x16x32_bf16(a1, qf[i][1], sacc[j2][i], 0, 0, 0);
      }
    }
    // ---- P = exp2(S): Q carried the scale; no mul, no row-sum VALU ----
    #pragma unroll
    for (int j2 = 0; j2 < 4; j2++)
      #pragma unroll
      for (int i = 0; i < 2; i++) {
        float p0 = EXP2(sacc[j2][i][0]);
        float p1 = EXP2(sacc[j2][i][1]);
        float p2 = EXP2(sacc[j2][i][2]);
        float p3 = EXP2(sacc[j2][i][3]);
        *(uint2*)&pw[(i * 16 + r) * 72 + j2 * 16 + q * 4] =
            make_uint2(pack2bf(p0, p1), pack2bf(p2, p3));
      }
    // ---- O += P @ V (own s-half); denom via MFMA with ones fragment ----
    #pragma unroll
    for (int ks = 0; ks < 2; ks++) {
      short8 pa0 = ld8(&pw[r * 72 + ks * 32 + q * 8]);
      short8 pa1 = ld8(&pw[(16 + r) * 72 + ks * 32 + q * 8]);
      den[0] = __builtin_amdgcn_mfma_f32_16x16x32_bf16(pa0, vone, den[0], 0, 0, 0);
      den[1] = __builtin_amdgcn_mfma_f32_16x16x32_bf16(pa1, vone, den[1], 0, 0, 0);
      #pragma unroll
      for (int dj = 0; dj < 4; dj++) {
        short8 vb = ld8(&Vs[(dj * 16 + r) * 128 + (((ws * 8 + ks * 4 + q) ^ r) * 8)]);
        oacc[0][dj] = __builtin_amdgcn_mfma_f32_16x16x32_bf16(pa0, vb, oacc[0][dj], 0, 0, 0);
        oacc[1][dj] = __builtin_amdgcn_mfma_f32_16x16x32_bf16(pa1, vb, oacc[1][dj], 0, 0, 0);
      }
    }
    __syncthreads();   // all waves done with Ks/Vs before next stage
  }

  // ---- cross-wave reduction between s-halves (LDS reused as f32 scratch) ----
  float* part = (float*)smem;            // [4 wq][2 half][32 col][36] f32
  float* dnf  = part + 8 * 32 * 36;      // [2 ws][4 wq][32] f32
  const int ho = 1 - ws;
  {
    const int wbase = (wq * 2 + ho) * 32;   // region owned by the partner
    #pragma unroll
    for (int i = 0; i < 2; i++) {
      if (ws == 0) {
        *(f32x4*)&part[(wbase + r) * 36 + i * 16 + q * 4]      = oacc[i][2];
        *(f32x4*)&part[(wbase + 16 + r) * 36 + i * 16 + q * 4] = oacc[i][3];
      } else {
        *(f32x4*)&part[(wbase + r) * 36 + i * 16 + q * 4]      = oacc[i][0];
        *(f32x4*)&part[(wbase + 16 + r) * 36 + i * 16 + q * 4] = oacc[i][1];
      }
      if (r == 0)
        *(f32x4*)&dnf[(ws * 4 + wq) * 32 + i * 16 + q * 4] = den[i];
    }
  }
  __syncthreads();
  {
    const int rbase = (wq * 2 + ws) * 32;   // our own region (partner wrote it)
    #pragma unroll
    for (int i = 0; i < 2; i++) {
      f32x4 dt = *(f32x4*)&dnf[(ho * 4 + wq) * 32 + i * 16 + q * 4] + den[i];
      f32x4 oa, ob;
      if (ws == 0) { oa = oacc[i][0]; ob = oacc[i][1]; }
      else         { oa = oacc[i][2]; ob = oacc[i][3]; }
      oa += *(f32x4*)&part[(rbase + r) * 36 + i * 16 + q * 4];
      ob += *(f32x4*)&part[(rbase + 16 + r) * 36 + i * 16 + q * 4];
      #pragma unroll
      for (int e = 0; e < 4; e++) {
        float di = 1.f / dt[e];
        int row = q0 + wq * 32 + i * 16 + q * 4 + e;
        u16* o = &attno[(size_t)(b * SS + row) * DIM + h * HD + ws * 32 + r];
        o[0]  = f2bf(oa[e] * di);
        o[16] = f2bf(ob[e] * di);
      }
    }
  }
}

extern "C" void kernel_launch(void* const* d_in, const int* in_sizes, int n_in,
                              void* d_out, int out_size, void* d_ws, size_t ws_size,
                              hipStream_t stream) {
  const float* x      = (const float*)d_in[0];
  const float* w_qkv  = (const float*)d_in[1];
  const float* b_qkv  = (const float*)d_in[2];
  const float* w_proj = (const float*)d_in[3];
  const float* b_proj = (const float*)d_in[4];
  float* out = (float*)d_out;
  char* ws = (char*)d_ws;
  // workspace layout (48 MB total)
  u16* xb     = (u16*)(ws);                       // [4096,1024]       8 MB
  u16* wqkvT  = (u16*)(ws + ((size_t)8  << 20));  // [3072,1024]       6 MB
  u16* wprojT = (u16*)(ws + ((size_t)14 << 20));  // [1024,1024]       2 MB
  u16* qk2    = (u16*)(ws + ((size_t)16 << 20));  // [4096,2048] Q,K  16 MB
  u16* attno  = (u16*)(ws + ((size_t)32 << 20));  // [4096,1024]       8 MB
  u16* vT     = (u16*)(ws + ((size_t)40 << 20));  // [2,16,64,2048]    8 MB

  cvt_kernel<<<4096, 256, 0, stream>>>(x, xb, MROWS * DIM / 4);
  tconv_kernel<<<dim3(48, 16), 256, 0, stream>>>(w_qkv, wqkvT, DIM, 3 * DIM);
  tconv_kernel<<<dim3(16, 16), 256, 0, stream>>>(w_proj, wprojT, DIM, DIM);
  gemm_bt<0><<<dim3(24, 32), 256, 0, stream>>>(xb, wqkvT, b_qkv, qk2, vT, MROWS, 3 * DIM, DIM);
  attn4_kernel<<<dim3(16, NH, BB), 512, 0, stream>>>(qk2, vT, attno);
  gemm_bt<1><<<dim3(8, 32), 256, 0, stream>>>(attno, wprojT, b_proj, out, nullptr, MROWS, DIM, DIM);
}

// Round 3
// 191.342 us; speedup vs baseline: 1.1295x; 1.0260x over previous
//
#include <hip/hip_runtime.h>
#include <hip/hip_bf16.h>

#define DIM 1024
#define NH 16
#define HD 64
#define BB 2
#define SS 2048
#define MROWS (BB * SS)   // 4096
#define SCALE 0.03125f    // 1024^-0.5
#define SC_LOG2E 0.04508422002778011f  // SCALE * log2(e)

typedef unsigned short u16;
typedef unsigned int u32;
typedef __attribute__((ext_vector_type(8))) short short8;
typedef __attribute__((ext_vector_type(4))) float f32x4;
typedef __attribute__((ext_vector_type(2))) unsigned int u32x2;

#if __has_builtin(__builtin_amdgcn_exp2f)
#define EXP2(x) __builtin_amdgcn_exp2f(x)
#else
#define EXP2(x) __builtin_exp2f(x)
#endif

__device__ __forceinline__ u16 f2bf(float f) {
  union { float f; u32 u; } v; v.f = f;
  return (u16)((v.u + 0x7fffu + ((v.u >> 16) & 1u)) >> 16);
}

__device__ __forceinline__ u32 pack2bf(float a, float b) {
  union { __hip_bfloat162 h; u32 u; } cv;
  cv.h = __float22bfloat162_rn(make_float2(a, b));
  return cv.u;
}

// permlane swaps: dst high row <-> src low row (row=32 / row=16 lanes)
__device__ __forceinline__ void plswap32(u32& a, u32& b) {
#if __has_builtin(__builtin_amdgcn_permlane32_swap)
  u32x2 t = __builtin_amdgcn_permlane32_swap(a, b, false, false);
  a = t[0]; b = t[1];
#else
  asm("v_permlane32_swap_b32 %0, %1" : "+v"(a), "+v"(b));
#endif
}
__device__ __forceinline__ void plswap16(u32& a, u32& b) {
#if __has_builtin(__builtin_amdgcn_permlane16_swap)
  u32x2 t = __builtin_amdgcn_permlane16_swap(a, b, false, false);
  a = t[0]; b = t[1];
#else
  asm("v_permlane16_swap_b32 %0, %1" : "+v"(a), "+v"(b));
#endif
}

__device__ __forceinline__ void async16(const u16* g, u16* l) {
  __builtin_amdgcn_global_load_lds(
      (const __attribute__((address_space(1))) void*)(const void*)g,
      (__attribute__((address_space(3))) void*)(void*)l, 16, 0, 0);
}

__device__ __forceinline__ short8 ld8(const u16* p) { return *(const short8*)p; }

// ---------------- fp32 -> bf16 convert (vectorized) ----------------
__global__ void cvt_kernel(const float* __restrict__ in, u16* __restrict__ out, int n4) {
  int i = blockIdx.x * blockDim.x + threadIdx.x;
  if (i < n4) {
    float4 v = ((const float4*)in)[i];
    u32 lo = (u32)f2bf(v.x) | ((u32)f2bf(v.y) << 16);
    u32 hi = (u32)f2bf(v.z) | ((u32)f2bf(v.w) << 16);
    ((uint2*)out)[i] = make_uint2(lo, hi);
  }
}

// ------- transpose + convert: in fp32 [R][C] -> out bf16 [C][R] -------
__global__ void tconv_kernel(const float* __restrict__ in, u16* __restrict__ out, int R, int C) {
  __shared__ u16 t[64 * 65];
  int c0 = blockIdx.x * 64, r0 = blockIdx.y * 64;
  #pragma unroll
  for (int i = 0; i < 16; i++) {
    int j = i * 256 + threadIdx.x;
    int rr = j >> 6, cc = j & 63;
    t[rr * 65 + cc] = f2bf(in[(size_t)(r0 + rr) * C + c0 + cc]);
  }
  __syncthreads();
  #pragma unroll
  for (int i = 0; i < 16; i++) {
    int j = i * 256 + threadIdx.x;
    int oc = j >> 6, orr = j & 63;
    out[(size_t)(c0 + oc) * R + r0 + orr] = t[orr * 65 + oc];
  }
}

// ------- bf16 GEMM, m97 structure: C[M,N] = A[M,K] @ Bt[N,K]^T + bias -------
// MODE 0: QKV gemm -> Q,K cols to qk2 [4096][2048] (stride-2048, V holes removed),
//         Q pre-scaled by SCALE*log2(e) so attn can use raw v_exp_f32.
//         V cols packed-transposed to vT [b][h][d][s].
// MODE 1: plain fp32 output [M][N].
template <int MODE>
__global__ __launch_bounds__(256, 2) void gemm_bt(
    const u16* __restrict__ A, const u16* __restrict__ Bt,
    const float* __restrict__ bias, void* __restrict__ C,
    u16* __restrict__ vT, int M, int N, int K) {
  __shared__ __align__(16) u16 As[128 * 32];
  __shared__ __align__(16) u16 Bs[128 * 32];
  const int tid = threadIdx.x;
  const int w = tid >> 6, l = tid & 63;
  const int r = l & 15, q = l >> 4;
  const int m0 = blockIdx.y * 128, n0 = blockIdx.x * 128;
  const int qm = (w & 1) * 64, qn = (w >> 1) * 64;

  const size_t aoff = (size_t)(m0 + w * 16 + (l >> 2)) * K + (size_t)(l & 3) * 8;
  const size_t boff = (size_t)(n0 + w * 16 + (l >> 2)) * K + (size_t)(l & 3) * 8;
  u16* alds = &As[(w * 64 + l) * 8];
  u16* blds = &Bs[(w * 64 + l) * 8];

  f32x4 acc[4][4] = {};
  for (int k0 = 0; k0 < K; k0 += 32) {
    async16(A + aoff + k0, alds);
    async16(A + aoff + (size_t)64 * K + k0, alds + 2048);
    async16(Bt + boff + k0, blds);
    async16(Bt + boff + (size_t)64 * K + k0, blds + 2048);
    __syncthreads();
    short8 af[4], bfr[4];
    #pragma unroll
    for (int i = 0; i < 4; i++) af[i] = ld8(&As[(qm + i * 16 + r) * 32 + q * 8]);
    #pragma unroll
    for (int j = 0; j < 4; j++) bfr[j] = ld8(&Bs[(qn + j * 16 + r) * 32 + q * 8]);
    #pragma unroll
    for (int i = 0; i < 4; i++)
      #pragma unroll
      for (int j = 0; j < 4; j++)
        acc[i][j] = __builtin_amdgcn_mfma_f32_16x16x32_bf16(af[i], bfr[j], acc[i][j], 0, 0, 0);
    __syncthreads();
  }
  // epilogue: C layout col = lane&15, row = quad*4 + reg
  #pragma unroll
  for (int i = 0; i < 4; i++) {
    int ro = m0 + qm + i * 16 + q * 4;
    #pragma unroll
    for (int j = 0; j < 4; j++) {
      int col = n0 + qn + j * 16 + r;
      float bv = bias[col];
      float v0 = acc[i][j][0] + bv, v1 = acc[i][j][1] + bv;
      float v2 = acc[i][j][2] + bv, v3 = acc[i][j][3] + bv;
      if (MODE == 1) {
        float* out = (float*)C;
        out[(size_t)(ro + 0) * N + col] = v0;
        out[(size_t)(ro + 1) * N + col] = v1;
        out[(size_t)(ro + 2) * N + col] = v2;
        out[(size_t)(ro + 3) * N + col] = v3;
      } else {
        int h = col / 192, wi = col - h * 192;
        if (wi >= 128) {
          // V: packed-transposed store, vT[((b*NH+h)*HD + d)*SS + s], 4 s's contiguous
          int bb = ro >> 11, s = ro & 2047, d = wi - 128;
          uint2 pk = make_uint2(pack2bf(v0, v1), pack2bf(v2, v3));
          *(uint2*)&vT[((size_t)((bb * NH + h) * HD + d)) * SS + s] = pk;
        } else {
          u16* qk2 = (u16*)C;
          const float sc = (wi < 64) ? SC_LOG2E : 1.0f;  // pre-scale Q only
          qk2[(size_t)(ro + 0) * 2048 + h * 128 + wi] = f2bf(v0 * sc);
          qk2[(size_t)(ro + 1) * 2048 + h * 128 + wi] = f2bf(v1 * sc);
          qk2[(size_t)(ro + 2) * 2048 + h * 128 + wi] = f2bf(v2 * sc);
          qk2[(size_t)(ro + 3) * 2048 + h * 128 + wi] = f2bf(v3 * sc);
        }
      }
    }
  }
}

// ------------------------- fused attention v5 -------------------------
// attn4 + two LDS-pipe cuts:
//  (a) P never touches LDS: the S^T C-layout -> PV A-fragment shuffle is done
//      in-register with permlane32_swap + permlane16_swap (VALU pipe, not DS).
//      Frees 36KB pb and removes 12 LDS ops/wave-tile.
//  (b) K/V double-buffered (2x32KB): next tile's global_load_lds issued BEFORE
//      computing the current tile; single __syncthreads per tile (its implicit
//      vmcnt(0) drains the prefetch). T3 minimum 2-phase recipe.
// Wave layout unchanged: 8 waves, wq=w&3 (32 q rows), ws=w>>2 (64-s half).
//
// Redistribution derivation: S^T C-layout gives lane(q,r) quad m=q (4 s vals,
// 2 packed words w0,w1) of s-16-block j2, for q-col r. PV A-frag needs
// lane(q,r) to hold s = ks*32 + q*8..+7 = quads 2(q&1),2(q&1)+1 of block
// j2'=2ks+(q>>1). With (X0,X1)=block-a words, (Y0,Y1)=block-b words:
// permlane32_swap(X,Y) moves block-a data to lanes q<2, block-b to q>=2;
// permlane16_swap(X,Y) then pairs quads {0,1}/{2,3} within each half.
// Result: pa words = [X0,X1,Y0,Y1] = [qA.w0, qA.w1, qB.w0, qB.w1].
__global__ __launch_bounds__(512, 4) void attn5_kernel(
    const u16* __restrict__ qk2, const u16* __restrict__ vT,
    u16* __restrict__ attno) {
  __shared__ __align__(16) u16 smem[32768];  // 65536B: buf0{Ks,Vs} | buf1{Ks,Vs}
  const int tid = threadIdx.x;
  const int w = tid >> 6, l = tid & 63;
  const int r = l & 15, q = l >> 4;
  const int wq = w & 3, ws = w >> 2;
  const int b = blockIdx.z, h = blockIdx.y, q0 = blockIdx.x * 128;

  const u16* qb = qk2 + (size_t)b * SS * 2048;
  const u16* kB = qb + h * 128 + 64;
  const u16* vB = vT + (size_t)((b * NH + h) * HD) * SS;

  // Q fragments (B-operand): rows q0+wq*32+i*16+r, k = kq*32+q*8 (pre-scaled)
  short8 qf[2][2];
  #pragma unroll
  for (int i = 0; i < 2; i++)
    #pragma unroll
    for (int kq = 0; kq < 2; kq++)
      qf[i][kq] = ld8(qb + (size_t)(q0 + wq * 32 + i * 16 + r) * 2048 + h * 128 + kq * 32 + q * 8);

  // staging lane constants
  const int klrow = l >> 3;                 // K: row within 8-row group
  const int kchunk = (l & 7) ^ klrow;       // K: swizzled global 16B-chunk
  const int vlrow = l >> 4;                 // V: row within 4-row group
  const int vslot = l & 15;                 // V: LDS slot

  // stage K tile (128x64) + V^T tile (64x128) into buffer at DST (4 instrs/wave)
#define STAGE(KV0, DST) do {                                                     \
    u16* Kd_ = (DST); u16* Vd_ = Kd_ + 8192;                                     \
    _Pragma("unroll")                                                            \
    for (int tt = 0; tt < 2; tt++) {                                             \
      int g = w * 2 + tt;                                                        \
      async16(kB + (size_t)((KV0) + g * 8 + klrow) * 2048 + kchunk * 8,          \
              &Kd_[g * 512 + l * 8]);                                            \
    }                                                                            \
    _Pragma("unroll")                                                            \
    for (int tt = 0; tt < 2; tt++) {                                             \
      int g = w * 2 + tt;                                                        \
      int d_ = g * 4 + vlrow;                                                    \
      int c_ = vslot ^ (d_ & 15);                                                \
      async16(vB + (size_t)d_ * SS + (KV0) + c_ * 8, &Vd_[g * 512 + l * 8]);     \
    }                                                                            \
  } while (0)

  const short8 vone = {0x3F80, 0x3F80, 0x3F80, 0x3F80, 0x3F80, 0x3F80, 0x3F80, 0x3F80};
  f32x4 oacc[2][4] = {};
  f32x4 den[2] = {};

  STAGE(0, smem);            // prologue: tile 0 -> buf 0
  __syncthreads();

  for (int t = 0; t < 16; ++t) {
    const int cur = t & 1;
    u16* Ks = smem + cur * 16384;
    u16* Vs = Ks + 8192;
    if (t < 15) STAGE((t + 1) * 128, smem + (cur ^ 1) * 16384);  // prefetch next

    // ---- S^T = K Q^T over own s-half: A = K rows (m=s), B = Q regs (n=q) ----
    f32x4 sacc[4][2] = {};
    #pragma unroll
    for (int j2 = 0; j2 < 4; j2++) {
      const u16* krow = &Ks[(ws * 64 + j2 * 16 + r) * 64];
      short8 a0 = ld8(krow + ((q ^ (r & 7)) * 8));
      short8 a1 = ld8(krow + (((4 + q) ^ (r & 7)) * 8));
      #pragma unroll
      for (int i = 0; i < 2; i++) {
        sacc[j2][i] = __builtin_amdgcn_mfma_f32_16x16x32_bf16(a0, qf[i][0], sacc[j2][i], 0, 0, 0);
        sacc[j2][i] = __builtin_amdgcn_mfma_f32_16x16x32_bf16(a1, qf[i][1], sacc[j2][i], 0, 0, 0);
      }
    }
    // ---- P = exp2(S), pack to bf16, redistribute in-register (no LDS) ----
    short8 pa[2][2];
    #pragma unroll
    for (int ks = 0; ks < 2; ks++)
      #pragma unroll
      for (int i = 0; i < 2; i++) {
        f32x4 sa = sacc[ks * 2][i], sb = sacc[ks * 2 + 1][i];
        u32 A0 = pack2bf(EXP2(sa[0]), EXP2(sa[1]));
        u32 A1 = pack2bf(EXP2(sa[2]), EXP2(sa[3]));
        u32 B0 = pack2bf(EXP2(sb[0]), EXP2(sb[1]));
        u32 B1 = pack2bf(EXP2(sb[2]), EXP2(sb[3]));
        plswap32(A0, B0);
        plswap32(A1, B1);
        plswap16(A0, B0);
        plswap16(A1, B1);
        union { short8 s8; u32 u[4]; } pk;
        pk.u[0] = A0; pk.u[1] = A1; pk.u[2] = B0; pk.u[3] = B1;
        pa[ks][i] = pk.s8;
      }
    // ---- O += P @ V (own s-half); denom via MFMA with ones fragment ----
    #pragma unroll
    for (int ks = 0; ks < 2; ks++) {
      den[0] = __builtin_amdgcn_mfma_f32_16x16x32_bf16(pa[ks][0], vone, den[0], 0, 0, 0);
      den[1] = __builtin_amdgcn_mfma_f32_16x16x32_bf16(pa[ks][1], vone, den[1], 0, 0, 0);
      #pragma unroll
      for (int dj = 0; dj < 4; dj++) {
        short8 vb = ld8(&Vs[(dj * 16 + r) * 128 + (((ws * 8 + ks * 4 + q) ^ r) * 8)]);
        oacc[0][dj] = __builtin_amdgcn_mfma_f32_16x16x32_bf16(pa[ks][0], vb, oacc[0][dj], 0, 0, 0);
        oacc[1][dj] = __builtin_amdgcn_mfma_f32_16x16x32_bf16(pa[ks][1], vb, oacc[1][dj], 0, 0, 0);
      }
    }
    __syncthreads();   // drains our prefetch (vmcnt 0) + all waves done with buf
  }
#undef STAGE

  // ---- cross-wave reduction between s-halves (LDS reused as f32 scratch) ----
  float* part = (float*)smem;            // [4 wq][2 half][32 col][36] f32
  float* dnf  = part + 8 * 32 * 36;      // [2 ws][4 wq][32] f32
  const int ho = 1 - ws;
  {
    const int wbase = (wq * 2 + ho) * 32;   // region owned by the partner
    #pragma unroll
    for (int i = 0; i < 2; i++) {
      if (ws == 0) {
        *(f32x4*)&part[(wbase + r) * 36 + i * 16 + q * 4]      = oacc[i][2];
        *(f32x4*)&part[(wbase + 16 + r) * 36 + i * 16 + q * 4] = oacc[i][3];
      } else {
        *(f32x4*)&part[(wbase + r) * 36 + i * 16 + q * 4]      = oacc[i][0];
        *(f32x4*)&part[(wbase + 16 + r) * 36 + i * 16 + q * 4] = oacc[i][1];
      }
      if (r == 0)
        *(f32x4*)&dnf[(ws * 4 + wq) * 32 + i * 16 + q * 4] = den[i];
    }
  }
  __syncthreads();
  {
    const int rbase = (wq * 2 + ws) * 32;   // our own region (partner wrote it)
    #pragma unroll
    for (int i = 0; i < 2; i++) {
      f32x4 dt = *(f32x4*)&dnf[(ho * 4 + wq) * 32 + i * 16 + q * 4] + den[i];
      f32x4 oa, ob;
      if (ws == 0) { oa = oacc[i][0]; ob = oacc[i][1]; }
      else         { oa = oacc[i][2]; ob = oacc[i][3]; }
      oa += *(f32x4*)&part[(rbase + r) * 36 + i * 16 + q * 4];
      ob += *(f32x4*)&part[(rbase + 16 + r) * 36 + i * 16 + q * 4];
      #pragma unroll
      for (int e = 0; e < 4; e++) {
        float di = 1.f / dt[e];
        int row = q0 + wq * 32 + i * 16 + q * 4 + e;
        u16* o = &attno[(size_t)(b * SS + row) * DIM + h * HD + ws * 32 + r];
        o[0]  = f2bf(oa[e] * di);
        o[16] = f2bf(ob[e] * di);
      }
    }
  }
}

extern "C" void kernel_launch(void* const* d_in, const int* in_sizes, int n_in,
                              void* d_out, int out_size, void* d_ws, size_t ws_size,
                              hipStream_t stream) {
  const float* x      = (const float*)d_in[0];
  const float* w_qkv  = (const float*)d_in[1];
  const float* b_qkv  = (const float*)d_in[2];
  const float* w_proj = (const float*)d_in[3];
  const float* b_proj = (const float*)d_in[4];
  float* out = (float*)d_out;
  char* ws = (char*)d_ws;
  // workspace layout (48 MB total)
  u16* xb     = (u16*)(ws);                       // [4096,1024]       8 MB
  u16* wqkvT  = (u16*)(ws + ((size_t)8  << 20));  // [3072,1024]       6 MB
  u16* wprojT = (u16*)(ws + ((size_t)14 << 20));  // [1024,1024]       2 MB
  u16* qk2    = (u16*)(ws + ((size_t)16 << 20));  // [4096,2048] Q,K  16 MB
  u16* attno  = (u16*)(ws + ((size_t)32 << 20));  // [4096,1024]       8 MB
  u16* vT     = (u16*)(ws + ((size_t)40 << 20));  // [2,16,64,2048]    8 MB

  cvt_kernel<<<4096, 256, 0, stream>>>(x, xb, MROWS * DIM / 4);
  tconv_kernel<<<dim3(48, 16), 256, 0, stream>>>(w_qkv, wqkvT, DIM, 3 * DIM);
  tconv_kernel<<<dim3(16, 16), 256, 0, stream>>>(w_proj, wprojT, DIM, DIM);
  gemm_bt<0><<<dim3(24, 32), 256, 0, stream>>>(xb, wqkvT, b_qkv, qk2, vT, MROWS, 3 * DIM, DIM);
  attn5_kernel<<<dim3(16, NH, BB), 512, 0, stream>>>(qk2, vT, attno);
  gemm_bt<1><<<dim3(8, 32), 256, 0, stream>>>(attno, wprojT, b_proj, out, nullptr, MROWS, DIM, DIM);
}

// Round 4
// 189.051 us; speedup vs baseline: 1.1431x; 1.0121x over previous
//
#include <hip/hip_runtime.h>
#include <hip/hip_bf16.h>

#define DIM 1024
#define NH 16
#define HD 64
#define BB 2
#define SS 2048
#define MROWS (BB * SS)   // 4096
#define SCALE 0.03125f    // 1024^-0.5
#define SC_LOG2E 0.04508422002778011f  // SCALE * log2(e)

typedef unsigned short u16;
typedef unsigned int u32;
typedef __attribute__((ext_vector_type(8))) short short8;
typedef __attribute__((ext_vector_type(4))) float f32x4;
typedef __attribute__((ext_vector_type(2))) unsigned int u32x2;

#if __has_builtin(__builtin_amdgcn_exp2f)
#define EXP2(x) __builtin_amdgcn_exp2f(x)
#else
#define EXP2(x) __builtin_exp2f(x)
#endif

__device__ __forceinline__ u16 f2bf(float f) {
  union { float f; u32 u; } v; v.f = f;
  return (u16)((v.u + 0x7fffu + ((v.u >> 16) & 1u)) >> 16);
}

__device__ __forceinline__ u32 pack2bf(float a, float b) {
  union { __hip_bfloat162 h; u32 u; } cv;
  cv.h = __float22bfloat162_rn(make_float2(a, b));
  return cv.u;
}

// permlane swaps: dst high row <-> src low row (row=32 / row=16 lanes)
__device__ __forceinline__ void plswap32(u32& a, u32& b) {
#if __has_builtin(__builtin_amdgcn_permlane32_swap)
  u32x2 t = __builtin_amdgcn_permlane32_swap(a, b, false, false);
  a = t[0]; b = t[1];
#else
  asm("v_permlane32_swap_b32 %0, %1" : "+v"(a), "+v"(b));
#endif
}
__device__ __forceinline__ void plswap16(u32& a, u32& b) {
#if __has_builtin(__builtin_amdgcn_permlane16_swap)
  u32x2 t = __builtin_amdgcn_permlane16_swap(a, b, false, false);
  a = t[0]; b = t[1];
#else
  asm("v_permlane16_swap_b32 %0, %1" : "+v"(a), "+v"(b));
#endif
}

__device__ __forceinline__ void async16(const u16* g, u16* l) {
  __builtin_amdgcn_global_load_lds(
      (const __attribute__((address_space(1))) void*)(const void*)g,
      (__attribute__((address_space(3))) void*)(void*)l, 16, 0, 0);
}

__device__ __forceinline__ short8 ld8(const u16* p) { return *(const short8*)p; }

// ---------------- fp32 -> bf16 convert (vectorized) ----------------
__global__ void cvt_kernel(const float* __restrict__ in, u16* __restrict__ out, int n4) {
  int i = blockIdx.x * blockDim.x + threadIdx.x;
  if (i < n4) {
    float4 v = ((const float4*)in)[i];
    u32 lo = (u32)f2bf(v.x) | ((u32)f2bf(v.y) << 16);
    u32 hi = (u32)f2bf(v.z) | ((u32)f2bf(v.w) << 16);
    ((uint2*)out)[i] = make_uint2(lo, hi);
  }
}

// ------- transpose + convert: in fp32 [R][C] -> out bf16 [C][R] -------
__global__ void tconv_kernel(const float* __restrict__ in, u16* __restrict__ out, int R, int C) {
  __shared__ u16 t[64 * 65];
  int c0 = blockIdx.x * 64, r0 = blockIdx.y * 64;
  #pragma unroll
  for (int i = 0; i < 16; i++) {
    int j = i * 256 + threadIdx.x;
    int rr = j >> 6, cc = j & 63;
    t[rr * 65 + cc] = f2bf(in[(size_t)(r0 + rr) * C + c0 + cc]);
  }
  __syncthreads();
  #pragma unroll
  for (int i = 0; i < 16; i++) {
    int j = i * 256 + threadIdx.x;
    int oc = j >> 6, orr = j & 63;
    out[(size_t)(c0 + oc) * R + r0 + orr] = t[orr * 65 + oc];
  }
}

// ------- bf16 GEMM, m97 structure: C[M,N] = A[M,K] @ Bt[N,K]^T + bias -------
// MODE 0: QKV gemm -> Q,K cols to qk2 [4096][2048] (stride-2048, V holes removed),
//         Q pre-scaled by SCALE*log2(e) so attn can use raw v_exp_f32.
//         V cols packed-transposed to vT [b][h][d][s].
// MODE 1: plain fp32 output [M][N].
template <int MODE>
__global__ __launch_bounds__(256, 2) void gemm_bt(
    const u16* __restrict__ A, const u16* __restrict__ Bt,
    const float* __restrict__ bias, void* __restrict__ C,
    u16* __restrict__ vT, int M, int N, int K) {
  __shared__ __align__(16) u16 As[128 * 32];
  __shared__ __align__(16) u16 Bs[128 * 32];
  const int tid = threadIdx.x;
  const int w = tid >> 6, l = tid & 63;
  const int r = l & 15, q = l >> 4;
  const int m0 = blockIdx.y * 128, n0 = blockIdx.x * 128;
  const int qm = (w & 1) * 64, qn = (w >> 1) * 64;

  const size_t aoff = (size_t)(m0 + w * 16 + (l >> 2)) * K + (size_t)(l & 3) * 8;
  const size_t boff = (size_t)(n0 + w * 16 + (l >> 2)) * K + (size_t)(l & 3) * 8;
  u16* alds = &As[(w * 64 + l) * 8];
  u16* blds = &Bs[(w * 64 + l) * 8];

  f32x4 acc[4][4] = {};
  for (int k0 = 0; k0 < K; k0 += 32) {
    async16(A + aoff + k0, alds);
    async16(A + aoff + (size_t)64 * K + k0, alds + 2048);
    async16(Bt + boff + k0, blds);
    async16(Bt + boff + (size_t)64 * K + k0, blds + 2048);
    __syncthreads();
    short8 af[4], bfr[4];
    #pragma unroll
    for (int i = 0; i < 4; i++) af[i] = ld8(&As[(qm + i * 16 + r) * 32 + q * 8]);
    #pragma unroll
    for (int j = 0; j < 4; j++) bfr[j] = ld8(&Bs[(qn + j * 16 + r) * 32 + q * 8]);
    #pragma unroll
    for (int i = 0; i < 4; i++)
      #pragma unroll
      for (int j = 0; j < 4; j++)
        acc[i][j] = __builtin_amdgcn_mfma_f32_16x16x32_bf16(af[i], bfr[j], acc[i][j], 0, 0, 0);
    __syncthreads();
  }
  // epilogue: C layout col = lane&15, row = quad*4 + reg
  #pragma unroll
  for (int i = 0; i < 4; i++) {
    int ro = m0 + qm + i * 16 + q * 4;
    #pragma unroll
    for (int j = 0; j < 4; j++) {
      int col = n0 + qn + j * 16 + r;
      float bv = bias[col];
      float v0 = acc[i][j][0] + bv, v1 = acc[i][j][1] + bv;
      float v2 = acc[i][j][2] + bv, v3 = acc[i][j][3] + bv;
      if (MODE == 1) {
        float* out = (float*)C;
        out[(size_t)(ro + 0) * N + col] = v0;
        out[(size_t)(ro + 1) * N + col] = v1;
        out[(size_t)(ro + 2) * N + col] = v2;
        out[(size_t)(ro + 3) * N + col] = v3;
      } else {
        int h = col / 192, wi = col - h * 192;
        if (wi >= 128) {
          // V: packed-transposed store, vT[((b*NH+h)*HD + d)*SS + s], 4 s's contiguous
          int bb = ro >> 11, s = ro & 2047, d = wi - 128;
          uint2 pk = make_uint2(pack2bf(v0, v1), pack2bf(v2, v3));
          *(uint2*)&vT[((size_t)((bb * NH + h) * HD + d)) * SS + s] = pk;
        } else {
          u16* qk2 = (u16*)C;
          const float sc = (wi < 64) ? SC_LOG2E : 1.0f;  // pre-scale Q only
          qk2[(size_t)(ro + 0) * 2048 + h * 128 + wi] = f2bf(v0 * sc);
          qk2[(size_t)(ro + 1) * 2048 + h * 128 + wi] = f2bf(v1 * sc);
          qk2[(size_t)(ro + 2) * 2048 + h * 128 + wi] = f2bf(v2 * sc);
          qk2[(size_t)(ro + 3) * 2048 + h * 128 + wi] = f2bf(v3 * sc);
        }
      }
    }
  }
}

// ------------------------- fused attention v6 -------------------------
// attn5 + three latency/locality changes (no layout or sync changes):
//  (a) T1 XCD-aware work swizzle: bijective remap of the 512 linear block IDs
//      so the 16 q-blocks sharing one (b,h)'s K/V land on ONE XCD
//      (xcd = lin%8 round-robin assumption; wrong assumption = perf-neutral).
//      4 bh-slices x 512KB = 2MB per XCD L2 (4MB) -> staged K/V become L2 hits.
//  (b) Intra-tile pipeline order: QKT(j2=0,1) -> conv pa0 -> QKT(j2=2,3) ->
//      PV(ks0) -> conv pa1 -> PV(ks1). Each VALU cluster sits between
//      independent MFMA clusters so VALU/MFMA pipes overlap.
//  (c) T5 s_setprio(1) around MFMA clusters.
__global__ __launch_bounds__(512, 4) void attn6_kernel(
    const u16* __restrict__ qk2, const u16* __restrict__ vT,
    u16* __restrict__ attno) {
  __shared__ __align__(16) u16 smem[32768];  // 65536B: buf0{Ks,Vs} | buf1{Ks,Vs}
  const int tid = threadIdx.x;
  const int w = tid >> 6, l = tid & 63;
  const int r = l & 15, q = l >> 4;
  const int wq = w & 3, ws = w >> 2;
  // XCD-aware bijective swizzle of (q-block, h, b)
  const int lin = blockIdx.x + 16 * (blockIdx.y + 16 * blockIdx.z);  // 0..511
  const int k8 = lin & 7, jj = lin >> 3;
  const int bh = ((jj >> 4) << 3) + k8;      // 0..31, constant per XCD group
  const int h = bh & 15, b = bh >> 4;
  const int q0 = (jj & 15) * 128;

  const u16* qb = qk2 + (size_t)b * SS * 2048;
  const u16* kB = qb + h * 128 + 64;
  const u16* vB = vT + (size_t)((b * NH + h) * HD) * SS;

  // Q fragments (B-operand): rows q0+wq*32+i*16+r, k = kq*32+q*8 (pre-scaled)
  short8 qf[2][2];
  #pragma unroll
  for (int i = 0; i < 2; i++)
    #pragma unroll
    for (int kq = 0; kq < 2; kq++)
      qf[i][kq] = ld8(qb + (size_t)(q0 + wq * 32 + i * 16 + r) * 2048 + h * 128 + kq * 32 + q * 8);

  // staging lane constants
  const int klrow = l >> 3;                 // K: row within 8-row group
  const int kchunk = (l & 7) ^ klrow;       // K: swizzled global 16B-chunk
  const int vlrow = l >> 4;                 // V: row within 4-row group
  const int vslot = l & 15;                 // V: LDS slot

  // stage K tile (128x64) + V^T tile (64x128) into buffer at DST (4 instrs/wave)
#define STAGE(KV0, DST) do {                                                     \
    u16* Kd_ = (DST); u16* Vd_ = Kd_ + 8192;                                     \
    _Pragma("unroll")                                                            \
    for (int tt = 0; tt < 2; tt++) {                                             \
      int g = w * 2 + tt;                                                        \
      async16(kB + (size_t)((KV0) + g * 8 + klrow) * 2048 + kchunk * 8,          \
              &Kd_[g * 512 + l * 8]);                                            \
    }                                                                            \
    _Pragma("unroll")                                                            \
    for (int tt = 0; tt < 2; tt++) {                                             \
      int g = w * 2 + tt;                                                        \
      int d_ = g * 4 + vlrow;                                                    \
      int c_ = vslot ^ (d_ & 15);                                                \
      async16(vB + (size_t)d_ * SS + (KV0) + c_ * 8, &Vd_[g * 512 + l * 8]);     \
    }                                                                            \
  } while (0)

  // convert sacc blocks (ks*2, ks*2+1) -> PV A-fragment pa[ks] (in-register)
#define CONV(ks) do {                                                            \
    _Pragma("unroll")                                                            \
    for (int i = 0; i < 2; i++) {                                                \
      f32x4 sa = sacc[(ks) * 2][i], sb = sacc[(ks) * 2 + 1][i];                  \
      u32 A0 = pack2bf(EXP2(sa[0]), EXP2(sa[1]));                                \
      u32 A1 = pack2bf(EXP2(sa[2]), EXP2(sa[3]));                                \
      u32 B0 = pack2bf(EXP2(sb[0]), EXP2(sb[1]));                                \
      u32 B1 = pack2bf(EXP2(sb[2]), EXP2(sb[3]));                                \
      plswap32(A0, B0);                                                          \
      plswap32(A1, B1);                                                          \
      plswap16(A0, B0);                                                          \
      plswap16(A1, B1);                                                          \
      union { short8 s8; u32 u[4]; } pk;                                         \
      pk.u[0] = A0; pk.u[1] = A1; pk.u[2] = B0; pk.u[3] = B1;                    \
      pa[ks][i] = pk.s8;                                                         \
    }                                                                            \
  } while (0)

#define QKT(j2) do {                                                             \
    const u16* krow = &Ks[(ws * 64 + (j2) * 16 + r) * 64];                       \
    short8 a0 = ld8(krow + ((q ^ (r & 7)) * 8));                                 \
    short8 a1 = ld8(krow + (((4 + q) ^ (r & 7)) * 8));                           \
    __builtin_amdgcn_s_setprio(1);                                               \
    _Pragma("unroll")                                                            \
    for (int i = 0; i < 2; i++) {                                                \
      sacc[j2][i] = __builtin_amdgcn_mfma_f32_16x16x32_bf16(a0, qf[i][0], sacc[j2][i], 0, 0, 0); \
      sacc[j2][i] = __builtin_amdgcn_mfma_f32_16x16x32_bf16(a1, qf[i][1], sacc[j2][i], 0, 0, 0); \
    }                                                                            \
    __builtin_amdgcn_s_setprio(0);                                               \
  } while (0)

#define PV(ks) do {                                                              \
    __builtin_amdgcn_s_setprio(1);                                               \
    den[0] = __builtin_amdgcn_mfma_f32_16x16x32_bf16(pa[ks][0], vone, den[0], 0, 0, 0); \
    den[1] = __builtin_amdgcn_mfma_f32_16x16x32_bf16(pa[ks][1], vone, den[1], 0, 0, 0); \
    _Pragma("unroll")                                                            \
    for (int dj = 0; dj < 4; dj++) {                                             \
      short8 vb = ld8(&Vs[(dj * 16 + r) * 128 + (((ws * 8 + (ks) * 4 + q) ^ r) * 8)]); \
      oacc[0][dj] = __builtin_amdgcn_mfma_f32_16x16x32_bf16(pa[ks][0], vb, oacc[0][dj], 0, 0, 0); \
      oacc[1][dj] = __builtin_amdgcn_mfma_f32_16x16x32_bf16(pa[ks][1], vb, oacc[1][dj], 0, 0, 0); \
    }                                                                            \
    __builtin_amdgcn_s_setprio(0);                                               \
  } while (0)

  const short8 vone = {0x3F80, 0x3F80, 0x3F80, 0x3F80, 0x3F80, 0x3F80, 0x3F80, 0x3F80};
  f32x4 oacc[2][4] = {};
  f32x4 den[2] = {};

  STAGE(0, smem);            // prologue: tile 0 -> buf 0
  __syncthreads();

  for (int t = 0; t < 16; ++t) {
    const int cur = t & 1;
    u16* Ks = smem + cur * 16384;
    u16* Vs = Ks + 8192;
    if (t < 15) STAGE((t + 1) * 128, smem + (cur ^ 1) * 16384);  // prefetch next

    f32x4 sacc[4][2] = {};
    short8 pa[2][2];
    // pipelined order: every VALU cluster sits between independent MFMA clusters
    QKT(0); QKT(1);
    CONV(0);               // overlaps QKT(2,3) below
    QKT(2); QKT(3);
    PV(0);                 // overlaps CONV(1) below
    CONV(1);
    PV(1);
    __syncthreads();   // drains our prefetch (vmcnt 0) + all waves done with buf
  }
#undef STAGE
#undef CONV
#undef QKT
#undef PV

  // ---- cross-wave reduction between s-halves (LDS reused as f32 scratch) ----
  float* part = (float*)smem;            // [4 wq][2 half][32 col][36] f32
  float* dnf  = part + 8 * 32 * 36;      // [2 ws][4 wq][32] f32
  const int ho = 1 - ws;
  {
    const int wbase = (wq * 2 + ho) * 32;   // region owned by the partner
    #pragma unroll
    for (int i = 0; i < 2; i++) {
      if (ws == 0) {
        *(f32x4*)&part[(wbase + r) * 36 + i * 16 + q * 4]      = oacc[i][2];
        *(f32x4*)&part[(wbase + 16 + r) * 36 + i * 16 + q * 4] = oacc[i][3];
      } else {
        *(f32x4*)&part[(wbase + r) * 36 + i * 16 + q * 4]      = oacc[i][0];
        *(f32x4*)&part[(wbase + 16 + r) * 36 + i * 16 + q * 4] = oacc[i][1];
      }
      if (r == 0)
        *(f32x4*)&dnf[(ws * 4 + wq) * 32 + i * 16 + q * 4] = den[i];
    }
  }
  __syncthreads();
  {
    const int rbase = (wq * 2 + ws) * 32;   // our own region (partner wrote it)
    #pragma unroll
    for (int i = 0; i < 2; i++) {
      f32x4 dt = *(f32x4*)&dnf[(ho * 4 + wq) * 32 + i * 16 + q * 4] + den[i];
      f32x4 oa, ob;
      if (ws == 0) { oa = oacc[i][0]; ob = oacc[i][1]; }
      else         { oa = oacc[i][2]; ob = oacc[i][3]; }
      oa += *(f32x4*)&part[(rbase + r) * 36 + i * 16 + q * 4];
      ob += *(f32x4*)&part[(rbase + 16 + r) * 36 + i * 16 + q * 4];
      #pragma unroll
      for (int e = 0; e < 4; e++) {
        float di = 1.f / dt[e];
        int row = q0 + wq * 32 + i * 16 + q * 4 + e;
        u16* o = &attno[(size_t)(b * SS + row) * DIM + h * HD + ws * 32 + r];
        o[0]  = f2bf(oa[e] * di);
        o[16] = f2bf(ob[e] * di);
      }
    }
  }
}

extern "C" void kernel_launch(void* const* d_in, const int* in_sizes, int n_in,
                              void* d_out, int out_size, void* d_ws, size_t ws_size,
                              hipStream_t stream) {
  const float* x      = (const float*)d_in[0];
  const float* w_qkv  = (const float*)d_in[1];
  const float* b_qkv  = (const float*)d_in[2];
  const float* w_proj = (const float*)d_in[3];
  const float* b_proj = (const float*)d_in[4];
  float* out = (float*)d_out;
  char* ws = (char*)d_ws;
  // workspace layout (48 MB total)
  u16* xb     = (u16*)(ws);                       // [4096,1024]       8 MB
  u16* wqkvT  = (u16*)(ws + ((size_t)8  << 20));  // [3072,1024]       6 MB
  u16* wprojT = (u16*)(ws + ((size_t)14 << 20));  // [1024,1024]       2 MB
  u16* qk2    = (u16*)(ws + ((size_t)16 << 20));  // [4096,2048] Q,K  16 MB
  u16* attno  = (u16*)(ws + ((size_t)32 << 20));  // [4096,1024]       8 MB
  u16* vT     = (u16*)(ws + ((size_t)40 << 20));  // [2,16,64,2048]    8 MB

  cvt_kernel<<<4096, 256, 0, stream>>>(x, xb, MROWS * DIM / 4);
  tconv_kernel<<<dim3(48, 16), 256, 0, stream>>>(w_qkv, wqkvT, DIM, 3 * DIM);
  tconv_kernel<<<dim3(16, 16), 256, 0, stream>>>(w_proj, wprojT, DIM, DIM);
  gemm_bt<0><<<dim3(24, 32), 256, 0, stream>>>(xb, wqkvT, b_qkv, qk2, vT, MROWS, 3 * DIM, DIM);
  attn6_kernel<<<dim3(16, NH, BB), 512, 0, stream>>>(qk2, vT, attno);
  gemm_bt<1><<<dim3(8, 32), 256, 0, stream>>>(attno, wprojT, b_proj, out, nullptr, MROWS, DIM, DIM);
}

// Round 6
// 181.901 us; speedup vs baseline: 1.1881x; 1.0393x over previous
//
#include <hip/hip_runtime.h>
#include <hip/hip_bf16.h>

#define DIM 1024
#define NH 16
#define HD 64
#define BB 2
#define SS 2048
#define MROWS (BB * SS)   // 4096
#define SCALE 0.03125f    // 1024^-0.5
#define SC_LOG2E 0.04508422002778011f  // SCALE * log2(e)

typedef unsigned short u16;
typedef unsigned int u32;
typedef __attribute__((ext_vector_type(8))) short short8;
typedef __attribute__((ext_vector_type(4))) float f32x4;
typedef __attribute__((ext_vector_type(2))) unsigned int u32x2;

#if __has_builtin(__builtin_amdgcn_exp2f)
#define EXP2(x) __builtin_amdgcn_exp2f(x)
#else
#define EXP2(x) __builtin_exp2f(x)
#endif

__device__ __forceinline__ u16 f2bf(float f) {
  union { float f; u32 u; } v; v.f = f;
  return (u16)((v.u + 0x7fffu + ((v.u >> 16) & 1u)) >> 16);
}

__device__ __forceinline__ u32 pack2bf(float a, float b) {
  union { __hip_bfloat162 h; u32 u; } cv;
  cv.h = __float22bfloat162_rn(make_float2(a, b));
  return cv.u;
}

// permlane swaps: dst high row <-> src low row (row=32 / row=16 lanes)
__device__ __forceinline__ void plswap32(u32& a, u32& b) {
#if __has_builtin(__builtin_amdgcn_permlane32_swap)
  u32x2 t = __builtin_amdgcn_permlane32_swap(a, b, false, false);
  a = t[0]; b = t[1];
#else
  asm("v_permlane32_swap_b32 %0, %1" : "+v"(a), "+v"(b));
#endif
}
__device__ __forceinline__ void plswap16(u32& a, u32& b) {
#if __has_builtin(__builtin_amdgcn_permlane16_swap)
  u32x2 t = __builtin_amdgcn_permlane16_swap(a, b, false, false);
  a = t[0]; b = t[1];
#else
  asm("v_permlane16_swap_b32 %0, %1" : "+v"(a), "+v"(b));
#endif
}

__device__ __forceinline__ void async16(const u16* g, u16* l) {
  __builtin_amdgcn_global_load_lds(
      (const __attribute__((address_space(1))) void*)(const void*)g,
      (__attribute__((address_space(3))) void*)(void*)l, 16, 0, 0);
}

__device__ __forceinline__ short8 ld8(const u16* p) { return *(const short8*)p; }

// ---------------- fp32 -> bf16 convert (vectorized) ----------------
__global__ void cvt_kernel(const float* __restrict__ in, u16* __restrict__ out, int n4) {
  int i = blockIdx.x * blockDim.x + threadIdx.x;
  if (i < n4) {
    float4 v = ((const float4*)in)[i];
    u32 lo = (u32)f2bf(v.x) | ((u32)f2bf(v.y) << 16);
    u32 hi = (u32)f2bf(v.z) | ((u32)f2bf(v.w) << 16);
    ((uint2*)out)[i] = make_uint2(lo, hi);
  }
}

// ------- transpose + convert: in fp32 [R][C] -> out bf16 [C][R] -------
__global__ void tconv_kernel(const float* __restrict__ in, u16* __restrict__ out, int R, int C) {
  __shared__ u16 t[64 * 65];
  int c0 = blockIdx.x * 64, r0 = blockIdx.y * 64;
  #pragma unroll
  for (int i = 0; i < 16; i++) {
    int j = i * 256 + threadIdx.x;
    int rr = j >> 6, cc = j & 63;
    t[rr * 65 + cc] = f2bf(in[(size_t)(r0 + rr) * C + c0 + cc]);
  }
  __syncthreads();
  #pragma unroll
  for (int i = 0; i < 16; i++) {
    int j = i * 256 + threadIdx.x;
    int oc = j >> 6, orr = j & 63;
    out[(size_t)(c0 + oc) * R + r0 + orr] = t[orr * 65 + oc];
  }
}

// ------- bf16 GEMM, prefetch-dbuf: C[M,N] = A[M,K] @ Bt[N,K]^T + bias -------
// T3-min 2-phase: STAGE(k0+32) into alternate LDS buffer BEFORE compute of k0;
// one barrier per K-step (implicit vmcnt/lgkm drain covers prefetch + frag reads).
// T1 XCD swizzle: grid flattened, bijective remap (nwg % 8 == 0), so consecutive
// row-panels of A stay on one XCD's L2. NXB = blocks per row-panel (N/128).
// MODE 0: QKV gemm -> Q,K cols to qk2 [4096][2048] (Q pre-scaled by SC_LOG2E),
//         V cols packed-transposed to vT [b][h][d][s].
// MODE 1: plain fp32 output [M][N].
template <int MODE, int NXB>
__global__ __launch_bounds__(256, 2) void gemm_bt(
    const u16* __restrict__ A, const u16* __restrict__ Bt,
    const float* __restrict__ bias, void* __restrict__ C,
    u16* __restrict__ vT, int M, int N, int K) {
  __shared__ __align__(16) u16 smem[16384];  // 32KB: 2 x (As 8KB + Bs 8KB)
  const int tid = threadIdx.x;
  const int w = tid >> 6, l = tid & 63;
  const int r = l & 15, q = l >> 4;
  // XCD-aware bijective remap (gridDim.x = nwg, nwg % 8 == 0)
  const int nwg = gridDim.x;
  const int cpx = nwg >> 3;
  const int lin = blockIdx.x;
  const int swz = (lin & 7) * cpx + (lin >> 3);
  const int m0 = (swz / NXB) * 128, n0 = (swz % NXB) * 128;
  const int qm = (w & 1) * 64, qn = (w >> 1) * 64;

  const size_t aoff = (size_t)(m0 + w * 16 + (l >> 2)) * K + (size_t)(l & 3) * 8;
  const size_t boff = (size_t)(n0 + w * 16 + (l >> 2)) * K + (size_t)(l & 3) * 8;
  const int soff = (w * 64 + l) * 8;   // == (w*16 + (l>>2))*32 + (l&3)*8

#define GSTAGE(K0, BASE) do {                                                    \
    u16* As_ = (BASE); u16* Bs_ = As_ + 4096;                                    \
    async16(A + aoff + (K0), As_ + soff);                                        \
    async16(A + aoff + (size_t)64 * K + (K0), As_ + soff + 2048);                \
    async16(Bt + boff + (K0), Bs_ + soff);                                       \
    async16(Bt + boff + (size_t)64 * K + (K0), Bs_ + soff + 2048);               \
  } while (0)

  f32x4 acc[4][4] = {};
  GSTAGE(0, smem);
  __syncthreads();
  for (int k0 = 0; k0 < K; k0 += 32) {
    u16* As = smem + ((k0 >> 5) & 1) * 8192;
    u16* Bs = As + 4096;
    if (k0 + 32 < K) GSTAGE(k0 + 32, smem + ((((k0 >> 5) & 1) ^ 1) * 8192));
    short8 af[4], bfr[4];
    #pragma unroll
    for (int i = 0; i < 4; i++) af[i] = ld8(&As[(qm + i * 16 + r) * 32 + q * 8]);
    #pragma unroll
    for (int j = 0; j < 4; j++) bfr[j] = ld8(&Bs[(qn + j * 16 + r) * 32 + q * 8]);
    #pragma unroll
    for (int i = 0; i < 4; i++)
      #pragma unroll
      for (int j = 0; j < 4; j++)
        acc[i][j] = __builtin_amdgcn_mfma_f32_16x16x32_bf16(af[i], bfr[j], acc[i][j], 0, 0, 0);
    __syncthreads();   // drains prefetch vmcnt + all waves done with this buf
  }
#undef GSTAGE
  // epilogue: C layout col = lane&15, row = quad*4 + reg
  #pragma unroll
  for (int i = 0; i < 4; i++) {
    int ro = m0 + qm + i * 16 + q * 4;
    #pragma unroll
    for (int j = 0; j < 4; j++) {
      int col = n0 + qn + j * 16 + r;
      float bv = bias[col];
      float v0 = acc[i][j][0] + bv, v1 = acc[i][j][1] + bv;
      float v2 = acc[i][j][2] + bv, v3 = acc[i][j][3] + bv;
      if (MODE == 1) {
        float* out = (float*)C;
        out[(size_t)(ro + 0) * N + col] = v0;
        out[(size_t)(ro + 1) * N + col] = v1;
        out[(size_t)(ro + 2) * N + col] = v2;
        out[(size_t)(ro + 3) * N + col] = v3;
      } else {
        int h = col / 192, wi = col - h * 192;
        if (wi >= 128) {
          // V: packed-transposed store, vT[((b*NH+h)*HD + d)*SS + s], 4 s's contiguous
          int bb = ro >> 11, s = ro & 2047, d = wi - 128;
          uint2 pk = make_uint2(pack2bf(v0, v1), pack2bf(v2, v3));
          *(uint2*)&vT[((size_t)((bb * NH + h) * HD + d)) * SS + s] = pk;
        } else {
          u16* qk2 = (u16*)C;
          const float sc = (wi < 64) ? SC_LOG2E : 1.0f;  // pre-scale Q only
          qk2[(size_t)(ro + 0) * 2048 + h * 128 + wi] = f2bf(v0 * sc);
          qk2[(size_t)(ro + 1) * 2048 + h * 128 + wi] = f2bf(v1 * sc);
          qk2[(size_t)(ro + 2) * 2048 + h * 128 + wi] = f2bf(v2 * sc);
          qk2[(size_t)(ro + 3) * 2048 + h * 128 + wi] = f2bf(v3 * sc);
        }
      }
    }
  }
}

// ------- bf16 GEMM, BM=128 x BN=64 tiles (for M>>N shapes, e.g. proj) -------
// Doubles grid size vs 128x128 (proj: 256 -> 512 blocks = 2 blocks/CU instead
// of 1 -> 2x latency hiding), smaller acc (32 regs) -> launch_bounds(256,4).
// Same prefetch-dbuf + XCD swizzle. fp32 output + bias.
__global__ __launch_bounds__(256, 4) void gemm_bt_n64(
    const u16* __restrict__ A, const u16* __restrict__ Bt,
    const float* __restrict__ bias, float* __restrict__ C,
    int M, int N, int K) {
  __shared__ __align__(16) u16 smem[12288];  // 24KB: 2 x (As 8KB + Bs 4KB)
  const int tid = threadIdx.x;
  const int w = tid >> 6, l = tid & 63;
  const int r = l & 15, q = l >> 4;
  const int NXB = N >> 6;
  const int nwg = gridDim.x;
  const int cpx = nwg >> 3;
  const int lin = blockIdx.x;
  const int swz = (lin & 7) * cpx + (lin >> 3);
  const int m0 = (swz / NXB) * 128, n0 = (swz % NXB) * 64;
  const int qm = (w & 1) * 64, qn = (w >> 1) * 32;

  const size_t aoff = (size_t)(m0 + w * 16 + (l >> 2)) * K + (size_t)(l & 3) * 8;
  const size_t boff = (size_t)(n0 + w * 16 + (l >> 2)) * K + (size_t)(l & 3) * 8;
  const int soff = (w * 64 + l) * 8;

#define NSTAGE(K0, BASE) do {                                                    \
    u16* As_ = (BASE); u16* Bs_ = As_ + 4096;                                    \
    async16(A + aoff + (K0), As_ + soff);                                        \
    async16(A + aoff + (size_t)64 * K + (K0), As_ + soff + 2048);                \
    async16(Bt + boff + (K0), Bs_ + soff);                                       \
  } while (0)

  f32x4 acc[4][2] = {};
  NSTAGE(0, smem);
  __syncthreads();
  for (int k0 = 0; k0 < K; k0 += 32) {
    u16* As = smem + ((k0 >> 5) & 1) * 6144;
    u16* Bs = As + 4096;
    if (k0 + 32 < K) NSTAGE(k0 + 32, smem + ((((k0 >> 5) & 1) ^ 1) * 6144));
    short8 af[4], bfr[2];
    #pragma unroll
    for (int i = 0; i < 4; i++) af[i] = ld8(&As[(qm + i * 16 + r) * 32 + q * 8]);
    #pragma unroll
    for (int j = 0; j < 2; j++) bfr[j] = ld8(&Bs[(qn + j * 16 + r) * 32 + q * 8]);
    #pragma unroll
    for (int i = 0; i < 4; i++)
      #pragma unroll
      for (int j = 0; j < 2; j++)
        acc[i][j] = __builtin_amdgcn_mfma_f32_16x16x32_bf16(af[i], bfr[j], acc[i][j], 0, 0, 0);
    __syncthreads();
  }
#undef NSTAGE
  #pragma unroll
  for (int i = 0; i < 4; i++) {
    int ro = m0 + qm + i * 16 + q * 4;
    #pragma unroll
    for (int j = 0; j < 2; j++) {
      int col = n0 + qn + j * 16 + r;
      float bv = bias[col];
      C[(size_t)(ro + 0) * N + col] = acc[i][j][0] + bv;
      C[(size_t)(ro + 1) * N + col] = acc[i][j][1] + bv;
      C[(size_t)(ro + 2) * N + col] = acc[i][j][2] + bv;
      C[(size_t)(ro + 3) * N + col] = acc[i][j][3] + bv;
    }
  }
}

// ------------------------- fused attention v6 -------------------------
// (unchanged from R4 passing version)
__global__ __launch_bounds__(512, 4) void attn6_kernel(
    const u16* __restrict__ qk2, const u16* __restrict__ vT,
    u16* __restrict__ attno) {
  __shared__ __align__(16) u16 smem[32768];  // 65536B: buf0{Ks,Vs} | buf1{Ks,Vs}
  const int tid = threadIdx.x;
  const int w = tid >> 6, l = tid & 63;
  const int r = l & 15, q = l >> 4;
  const int wq = w & 3, ws = w >> 2;
  // XCD-aware bijective swizzle of (q-block, h, b)
  const int lin = blockIdx.x + 16 * (blockIdx.y + 16 * blockIdx.z);  // 0..511
  const int k8 = lin & 7, jj = lin >> 3;
  const int bh = ((jj >> 4) << 3) + k8;      // 0..31, constant per XCD group
  const int h = bh & 15, b = bh >> 4;
  const int q0 = (jj & 15) * 128;

  const u16* qb = qk2 + (size_t)b * SS * 2048;
  const u16* kB = qb + h * 128 + 64;
  const u16* vB = vT + (size_t)((b * NH + h) * HD) * SS;

  // Q fragments (B-operand): rows q0+wq*32+i*16+r, k = kq*32+q*8 (pre-scaled)
  short8 qf[2][2];
  #pragma unroll
  for (int i = 0; i < 2; i++)
    #pragma unroll
    for (int kq = 0; kq < 2; kq++)
      qf[i][kq] = ld8(qb + (size_t)(q0 + wq * 32 + i * 16 + r) * 2048 + h * 128 + kq * 32 + q * 8);

  // staging lane constants
  const int klrow = l >> 3;                 // K: row within 8-row group
  const int kchunk = (l & 7) ^ klrow;       // K: swizzled global 16B-chunk
  const int vlrow = l >> 4;                 // V: row within 4-row group
  const int vslot = l & 15;                 // V: LDS slot

#define STAGE(KV0, DST) do {                                                     \
    u16* Kd_ = (DST); u16* Vd_ = Kd_ + 8192;                                     \
    _Pragma("unroll")                                                            \
    for (int tt = 0; tt < 2; tt++) {                                             \
      int g = w * 2 + tt;                                                        \
      async16(kB + (size_t)((KV0) + g * 8 + klrow) * 2048 + kchunk * 8,          \
              &Kd_[g * 512 + l * 8]);                                            \
    }                                                                            \
    _Pragma("unroll")                                                            \
    for (int tt = 0; tt < 2; tt++) {                                             \
      int g = w * 2 + tt;                                                        \
      int d_ = g * 4 + vlrow;                                                    \
      int c_ = vslot ^ (d_ & 15);                                                \
      async16(vB + (size_t)d_ * SS + (KV0) + c_ * 8, &Vd_[g * 512 + l * 8]);     \
    }                                                                            \
  } while (0)

#define CONV(ks) do {                                                            \
    _Pragma("unroll")                                                            \
    for (int i = 0; i < 2; i++) {                                                \
      f32x4 sa = sacc[(ks) * 2][i], sb = sacc[(ks) * 2 + 1][i];                  \
      u32 A0 = pack2bf(EXP2(sa[0]), EXP2(sa[1]));                                \
      u32 A1 = pack2bf(EXP2(sa[2]), EXP2(sa[3]));                                \
      u32 B0 = pack2bf(EXP2(sb[0]), EXP2(sb[1]));                                \
      u32 B1 = pack2bf(EXP2(sb[2]), EXP2(sb[3]));                                \
      plswap32(A0, B0);                                                          \
      plswap32(A1, B1);                                                          \
      plswap16(A0, B0);                                                          \
      plswap16(A1, B1);                                                          \
      union { short8 s8; u32 u[4]; } pk;                                         \
      pk.u[0] = A0; pk.u[1] = A1; pk.u[2] = B0; pk.u[3] = B1;                    \
      pa[ks][i] = pk.s8;                                                         \
    }                                                                            \
  } while (0)

#define QKT(j2) do {                                                             \
    const u16* krow = &Ks[(ws * 64 + (j2) * 16 + r) * 64];                       \
    short8 a0 = ld8(krow + ((q ^ (r & 7)) * 8));                                 \
    short8 a1 = ld8(krow + (((4 + q) ^ (r & 7)) * 8));                           \
    __builtin_amdgcn_s_setprio(1);                                               \
    _Pragma("unroll")                                                            \
    for (int i = 0; i < 2; i++) {                                                \
      sacc[j2][i] = __builtin_amdgcn_mfma_f32_16x16x32_bf16(a0, qf[i][0], sacc[j2][i], 0, 0, 0); \
      sacc[j2][i] = __builtin_amdgcn_mfma_f32_16x16x32_bf16(a1, qf[i][1], sacc[j2][i], 0, 0, 0); \
    }                                                                            \
    __builtin_amdgcn_s_setprio(0);                                               \
  } while (0)

#define PV(ks) do {                                                              \
    __builtin_amdgcn_s_setprio(1);                                               \
    den[0] = __builtin_amdgcn_mfma_f32_16x16x32_bf16(pa[ks][0], vone, den[0], 0, 0, 0); \
    den[1] = __builtin_amdgcn_mfma_f32_16x16x32_bf16(pa[ks][1], vone, den[1], 0, 0, 0); \
    _Pragma("unroll")                                                            \
    for (int dj = 0; dj < 4; dj++) {                                             \
      short8 vb = ld8(&Vs[(dj * 16 + r) * 128 + (((ws * 8 + (ks) * 4 + q) ^ r) * 8)]); \
      oacc[0][dj] = __builtin_amdgcn_mfma_f32_16x16x32_bf16(pa[ks][0], vb, oacc[0][dj], 0, 0, 0); \
      oacc[1][dj] = __builtin_amdgcn_mfma_f32_16x16x32_bf16(pa[ks][1], vb, oacc[1][dj], 0, 0, 0); \
    }                                                                            \
    __builtin_amdgcn_s_setprio(0);                                               \
  } while (0)

  const short8 vone = {0x3F80, 0x3F80, 0x3F80, 0x3F80, 0x3F80, 0x3F80, 0x3F80, 0x3F80};
  f32x4 oacc[2][4] = {};
  f32x4 den[2] = {};

  STAGE(0, smem);            // prologue: tile 0 -> buf 0
  __syncthreads();

  for (int t = 0; t < 16; ++t) {
    const int cur = t & 1;
    u16* Ks = smem + cur * 16384;
    u16* Vs = Ks + 8192;
    if (t < 15) STAGE((t + 1) * 128, smem + (cur ^ 1) * 16384);  // prefetch next

    f32x4 sacc[4][2] = {};
    short8 pa[2][2];
    // pipelined order: every VALU cluster sits between independent MFMA clusters
    QKT(0); QKT(1);
    CONV(0);               // overlaps QKT(2,3) below
    QKT(2); QKT(3);
    PV(0);                 // overlaps CONV(1) below
    CONV(1);
    PV(1);
    __syncthreads();   // drains our prefetch (vmcnt 0) + all waves done with buf
  }
#undef STAGE
#undef CONV
#undef QKT
#undef PV

  // ---- cross-wave reduction between s-halves (LDS reused as f32 scratch) ----
  float* part = (float*)smem;            // [4 wq][2 half][32 col][36] f32
  float* dnf  = part + 8 * 32 * 36;      // [2 ws][4 wq][32] f32
  const int ho = 1 - ws;
  {
    const int wbase = (wq * 2 + ho) * 32;   // region owned by the partner
    #pragma unroll
    for (int i = 0; i < 2; i++) {
      if (ws == 0) {
        *(f32x4*)&part[(wbase + r) * 36 + i * 16 + q * 4]      = oacc[i][2];
        *(f32x4*)&part[(wbase + 16 + r) * 36 + i * 16 + q * 4] = oacc[i][3];
      } else {
        *(f32x4*)&part[(wbase + r) * 36 + i * 16 + q * 4]      = oacc[i][0];
        *(f32x4*)&part[(wbase + 16 + r) * 36 + i * 16 + q * 4] = oacc[i][1];
      }
      if (r == 0)
        *(f32x4*)&dnf[(ws * 4 + wq) * 32 + i * 16 + q * 4] = den[i];
    }
  }
  __syncthreads();
  {
    const int rbase = (wq * 2 + ws) * 32;   // our own region (partner wrote it)
    #pragma unroll
    for (int i = 0; i < 2; i++) {
      f32x4 dt = *(f32x4*)&dnf[(ho * 4 + wq) * 32 + i * 16 + q * 4] + den[i];
      f32x4 oa, ob;
      if (ws == 0) { oa = oacc[i][0]; ob = oacc[i][1]; }
      else         { oa = oacc[i][2]; ob = oacc[i][3]; }
      oa += *(f32x4*)&part[(rbase + r) * 36 + i * 16 + q * 4];
      ob += *(f32x4*)&part[(rbase + 16 + r) * 36 + i * 16 + q * 4];
      #pragma unroll
      for (int e = 0; e < 4; e++) {
        float di = 1.f / dt[e];
        int row = q0 + wq * 32 + i * 16 + q * 4 + e;
        u16* o = &attno[(size_t)(b * SS + row) * DIM + h * HD + ws * 32 + r];
        o[0]  = f2bf(oa[e] * di);
        o[16] = f2bf(ob[e] * di);
      }
    }
  }
}

extern "C" void kernel_launch(void* const* d_in, const int* in_sizes, int n_in,
                              void* d_out, int out_size, void* d_ws, size_t ws_size,
                              hipStream_t stream) {
  const float* x      = (const float*)d_in[0];
  const float* w_qkv  = (const float*)d_in[1];
  const float* b_qkv  = (const float*)d_in[2];
  const float* w_proj = (const float*)d_in[3];
  const float* b_proj = (const float*)d_in[4];
  float* out = (float*)d_out;
  char* ws = (char*)d_ws;
  // workspace layout (48 MB total)
  u16* xb     = (u16*)(ws);                       // [4096,1024]       8 MB
  u16* wqkvT  = (u16*)(ws + ((size_t)8  << 20));  // [3072,1024]       6 MB
  u16* wprojT = (u16*)(ws + ((size_t)14 << 20));  // [1024,1024]       2 MB
  u16* qk2    = (u16*)(ws + ((size_t)16 << 20));  // [4096,2048] Q,K  16 MB
  u16* attno  = (u16*)(ws + ((size_t)32 << 20));  // [4096,1024]       8 MB
  u16* vT     = (u16*)(ws + ((size_t)40 << 20));  // [2,16,64,2048]    8 MB

  cvt_kernel<<<4096, 256, 0, stream>>>(x, xb, MROWS * DIM / 4);
  tconv_kernel<<<dim3(48, 16), 256, 0, stream>>>(w_qkv, wqkvT, DIM, 3 * DIM);
  tconv_kernel<<<dim3(16, 16), 256, 0, stream>>>(w_proj, wprojT, DIM, DIM);
  // QKV: grid flattened 24x32 = 768 blocks (768 % 8 == 0), NXB = 3072/128 = 24
  gemm_bt<0, 24><<<768, 256, 0, stream>>>(xb, wqkvT, b_qkv, qk2, vT, MROWS, 3 * DIM, DIM);
  attn6_kernel<<<dim3(16, NH, BB), 512, 0, stream>>>(qk2, vT, attno);
  // proj: BM=128 x BN=64 tiles -> 16*32 = 512 blocks (2 blocks/CU)
  gemm_bt_n64<<<512, 256, 0, stream>>>(attno, wprojT, b_proj, out, MROWS, DIM, DIM);
}